// Round 13
// baseline (957.903 us; speedup 1.0000x reference)
//
#include <hip/hip_runtime.h>
#include <math.h>

#define D_MODEL 1024
#define NH      16
#define DHEAD   64
#define LDK     32   // GEMM LDS K-stride (bf16) — LINEAR (global_load_lds requires it)
#define LDA     72   // attn LDS row stride (bf16) -> 144B rows, 16B-aligned, ~2-way banks

typedef __attribute__((ext_vector_type(8))) short bf16x8;
typedef __attribute__((ext_vector_type(4))) float f32x4;

__device__ __forceinline__ unsigned short f2b(float f) {
    union { float f; unsigned u; } v; v.f = f;
    unsigned r = v.u + 0x7FFFu + ((v.u >> 16) & 1u);   // RNE
    return (unsigned short)(r >> 16);
}
__device__ __forceinline__ float gelu_exact(float x) {
    return 0.5f * x * (1.0f + erff(x * 0.70710678118654752440f));
}
// async global->LDS, 16B per lane; LDS dest = wave-uniform base + lane*16 (m104)
__device__ __forceinline__ void gload_lds16(const unsigned short* g, unsigned short* l) {
    __builtin_amdgcn_global_load_lds(
        (const __attribute__((address_space(1))) void*)g,
        (__attribute__((address_space(3))) void*)l, 16, 0, 0);
}

// ---------------------------------------------------------------------------
// LayerNorm: fp32 in, bf16 out (feeds MFMA GEMMs)
// ---------------------------------------------------------------------------
__global__ __launch_bounds__(256) void ln_kernel(
    const float* __restrict__ X, const float* __restrict__ g,
    const float* __restrict__ bta, unsigned short* __restrict__ Y)
{
    __shared__ float red[8];
    const int row = blockIdx.x;
    const int tid = threadIdx.x;
    const float* x = X + (size_t)row * D_MODEL;

    float4 v = *(const float4*)&x[tid * 4];
    float s  = v.x + v.y + v.z + v.w;
    float sq = v.x * v.x + v.y * v.y + v.z * v.z + v.w * v.w;
#pragma unroll
    for (int o = 32; o > 0; o >>= 1) {
        s  += __shfl_down(s, o);
        sq += __shfl_down(sq, o);
    }
    if ((tid & 63) == 0) { red[tid >> 6] = s; red[4 + (tid >> 6)] = sq; }
    __syncthreads();
    const float ts = red[0] + red[1] + red[2] + red[3];
    const float tq = red[4] + red[5] + red[6] + red[7];
    const float mu   = ts * (1.0f / D_MODEL);
    const float var  = tq * (1.0f / D_MODEL) - mu * mu;
    const float rstd = 1.0f / sqrtf(var + 1e-5f);

    const float4 gv = *(const float4*)&g[tid * 4];
    const float4 bv = *(const float4*)&bta[tid * 4];
    ushort4 y;
    y.x = f2b((v.x - mu) * rstd * gv.x + bv.x);
    y.y = f2b((v.y - mu) * rstd * gv.y + bv.y);
    y.z = f2b((v.z - mu) * rstd * gv.z + bv.z);
    y.w = f2b((v.w - mu) * rstd * gv.w + bv.w);
    *(ushort4*)&Y[(size_t)row * D_MODEL + tid * 4] = y;
}

// ---------------------------------------------------------------------------
// fp32 -> bf16 elementwise (for xa)
// ---------------------------------------------------------------------------
__global__ __launch_bounds__(256) void f2b_kernel(
    const float* __restrict__ in, unsigned short* __restrict__ out, int n4)
{
    int i = blockIdx.x * blockDim.x + threadIdx.x;
    for (; i < n4; i += gridDim.x * blockDim.x) {
        float4 v = ((const float4*)in)[i];
        ushort4 o; o.x = f2b(v.x); o.y = f2b(v.y); o.z = f2b(v.z); o.w = f2b(v.w);
        ((ushort4*)out)[i] = o;
    }
}

// ---------------------------------------------------------------------------
// Weight transpose+convert: W[K][N] fp32 -> Wt[N][K] bf16
// ---------------------------------------------------------------------------
__global__ __launch_bounds__(256) void wtrans_kernel(
    const float* __restrict__ W, unsigned short* __restrict__ Wt, int K, int N)
{
    __shared__ float t[32][33];
    const int n0 = blockIdx.x * 32, k0 = blockIdx.y * 32;
    const int tx = threadIdx.x, ty = threadIdx.y;  // (32, 8)
#pragma unroll
    for (int i = 0; i < 4; ++i)
        t[ty + i * 8][tx] = W[(size_t)(k0 + ty + i * 8) * N + n0 + tx];
    __syncthreads();
#pragma unroll
    for (int i = 0; i < 4; ++i)
        Wt[(size_t)(n0 + ty + i * 8) * K + k0 + tx] = f2b(t[tx][ty + i * 8]);
}

// ---------------------------------------------------------------------------
// BF16 MFMA GEMM: C[M,N] = A[M,K] @ Wt[N,K]^T (+bias)(+resid)(+GELU)
// 128x128 tile, BK=32, 256 thr = 4 waves (2x2 of 64x64), 16x16x32 MFMA.
// Staging via global_load_lds width=16 (m97 structure): LDS linear [128][32],
// wave w stages segments 2w,2w+1 (16 rows each); lane l -> row s*16+(l>>2),
// col (l&3)*8  ==  LDS bytes s*1024 + l*16 (verified: (l>>2)*64+(l&3)*16 = 16l).
// ---------------------------------------------------------------------------
template <bool GELU, bool OBF16>
__global__ __launch_bounds__(256) void mfma_gemm(
    const unsigned short* __restrict__ A, const unsigned short* __restrict__ Wt,
    const float* __restrict__ bias, const float* __restrict__ resid,
    void* __restrict__ C, int M, int N, int K)
{
    __shared__ unsigned short As[128 * LDK];
    __shared__ unsigned short Bs[128 * LDK];

    const int tid  = threadIdx.x;
    const int row0 = blockIdx.y * 128;
    const int col0 = blockIdx.x * 128;
    const int l = tid & 63, w = tid >> 6;
    const int wr = (w >> 1) * 64, wc = (w & 1) * 64;

    // staging: wave-owned segments (wave-uniform LDS bases)
    const int s0 = w * 2, s1 = w * 2 + 1;
    const int lrow0 = s0 * 16 + (l >> 2);      // global row offset, segment 0
    const int lrow1 = s1 * 16 + (l >> 2);
    const int lcol  = (l & 3) * 8;             // elem offset within 32-elem K-slab
    const unsigned short* Ap0 = A  + (size_t)(row0 + lrow0) * K + lcol;
    const unsigned short* Ap1 = A  + (size_t)(row0 + lrow1) * K + lcol;
    const unsigned short* Bp0 = Wt + (size_t)(col0 + lrow0) * K + lcol;
    const unsigned short* Bp1 = Wt + (size_t)(col0 + lrow1) * K + lcol;
    unsigned short* ldsA0 = As + s0 * 512;     // 512 elems = 1024 B per segment
    unsigned short* ldsA1 = As + s1 * 512;
    unsigned short* ldsB0 = Bs + s0 * 512;
    unsigned short* ldsB1 = Bs + s1 * 512;

    f32x4 acc[4][4] = {};
    const int fr = l & 15, fk = (l >> 4) * 8;

    for (int kt = 0; kt < K; kt += 32) {
        __syncthreads();                       // prev tile reads done
        gload_lds16(Ap0 + kt, ldsA0);
        gload_lds16(Ap1 + kt, ldsA1);
        gload_lds16(Bp0 + kt, ldsB0);
        gload_lds16(Bp1 + kt, ldsB1);
        __syncthreads();                       // vmcnt(0) drain -> tile resident

        bf16x8 af[4], bf[4];
#pragma unroll
        for (int m = 0; m < 4; ++m)
            af[m] = *(const bf16x8*)&As[(wr + m * 16 + fr) * LDK + fk];
#pragma unroll
        for (int n = 0; n < 4; ++n)
            bf[n] = *(const bf16x8*)&Bs[(wc + n * 16 + fr) * LDK + fk];
#pragma unroll
        for (int m = 0; m < 4; ++m)
#pragma unroll
            for (int n = 0; n < 4; ++n)
                acc[m][n] = __builtin_amdgcn_mfma_f32_16x16x32_bf16(
                    af[m], bf[n], acc[m][n], 0, 0, 0);
    }

    // epilogue: C/D layout col=l&15, row=(l>>4)*4+i  [verified m89 + round-9/12 pass]
    const int fq = l >> 4;
#pragma unroll
    for (int m = 0; m < 4; ++m) {
#pragma unroll
        for (int i = 0; i < 4; ++i) {
            const int r = row0 + wr + m * 16 + fq * 4 + i;
            if (r < M) {
#pragma unroll
                for (int n = 0; n < 4; ++n) {
                    const int c = col0 + wc + n * 16 + fr;
                    float v = acc[m][n][i];
                    if (bias)  v += bias[c];
                    if (resid) v += resid[(size_t)r * N + c];
                    if (GELU)  v = gelu_exact(v);
                    if (OBF16) ((unsigned short*)C)[(size_t)r * N + c] = f2b(v);
                    else       ((float*)C)[(size_t)r * N + c] = v;
                }
            }
        }
    }
}

// ---------------------------------------------------------------------------
// MFMA flash attention: bf16 Q/K/V in, bf16 O out, fp32 softmax/accum.
// (unchanged from round 12 — validated at 136 us cross / absmax 0.03125)
// ---------------------------------------------------------------------------
template <bool CAUSAL>
__global__ __launch_bounds__(256) void mfattn_kernel(
    const unsigned short* __restrict__ Q, const unsigned short* __restrict__ K,
    const unsigned short* __restrict__ V, unsigned short* __restrict__ O,
    int Sq, int Sk)
{
    __shared__ unsigned short Qs[64 * LDA];
    __shared__ unsigned short Ks[64 * LDA];
    __shared__ unsigned short Vt[64 * LDA];   // V transposed: [d][k]
    __shared__ unsigned short Ps[64 * LDA];   // P bf16: [q][k]

    const int qt  = blockIdx.x;
    const int h   = blockIdx.y;
    const int b   = blockIdx.z;
    const int tid = threadIdx.x;
    const int l   = tid & 63, w = tid >> 6;
    const int fr  = l & 15;            // fragment row/col index
    const int fk  = (l >> 4) * 8;      // fragment k offset
    const int fq  = l >> 4;            // C/D row group

    const int srow = tid >> 2;         // 0..63
    const int sc8  = (tid & 3) * 16;   // 0,16,32,48

    {
        const unsigned short* qg =
            Q + ((size_t)(b * Sq + qt * 64 + srow)) * D_MODEL + h * DHEAD;
        *(uint4*)&Qs[srow * LDA + sc8]     = *(const uint4*)&qg[sc8];
        *(uint4*)&Qs[srow * LDA + sc8 + 8] = *(const uint4*)&qg[sc8 + 8];
    }
    __syncthreads();

    bf16x8 aq0 = *(const bf16x8*)&Qs[(w * 16 + fr) * LDA + fk];
    bf16x8 aq1 = *(const bf16x8*)&Qs[(w * 16 + fr) * LDA + 32 + fk];

    f32x4 o_acc[4] = {};
    float m_run[4], l_run[4];
#pragma unroll
    for (int i = 0; i < 4; ++i) { m_run[i] = -INFINITY; l_run[i] = 0.0f; }

    const int rg0 = qt * 64 + w * 16 + fq * 4;
    const int nkt = CAUSAL ? (qt + 1) : ((Sk + 63) >> 6);

    for (int kt = 0; kt < nkt; ++kt) {
        __syncthreads();
        {
            const int kr = kt * 64 + srow;
            if (!CAUSAL && kr >= Sk) {
                const uint4 z = make_uint4(0, 0, 0, 0);
                *(uint4*)&Ks[srow * LDA + sc8]     = z;
                *(uint4*)&Ks[srow * LDA + sc8 + 8] = z;
#pragma unroll
                for (int u = 0; u < 16; ++u) Vt[(sc8 + u) * LDA + srow] = 0;
            } else {
                const unsigned short* kg =
                    K + ((size_t)(b * Sk + kr)) * D_MODEL + h * DHEAD;
                const unsigned short* vg =
                    V + ((size_t)(b * Sk + kr)) * D_MODEL + h * DHEAD;
                *(uint4*)&Ks[srow * LDA + sc8]     = *(const uint4*)&kg[sc8];
                *(uint4*)&Ks[srow * LDA + sc8 + 8] = *(const uint4*)&kg[sc8 + 8];
                union { uint4 v; unsigned short s[8]; } v0, v1;
                v0.v = *(const uint4*)&vg[sc8];
                v1.v = *(const uint4*)&vg[sc8 + 8];
#pragma unroll
                for (int u = 0; u < 8; ++u) {
                    Vt[(sc8 + u) * LDA + srow]     = v0.s[u];
                    Vt[(sc8 + 8 + u) * LDA + srow] = v1.s[u];
                }
            }
        }
        __syncthreads();

        f32x4 s_acc[4] = {};
#pragma unroll
        for (int n = 0; n < 4; ++n) {
            bf16x8 bk0 = *(const bf16x8*)&Ks[(n * 16 + fr) * LDA + fk];
            bf16x8 bk1 = *(const bf16x8*)&Ks[(n * 16 + fr) * LDA + 32 + fk];
            s_acc[n] = __builtin_amdgcn_mfma_f32_16x16x32_bf16(aq0, bk0, s_acc[n], 0, 0, 0);
            s_acc[n] = __builtin_amdgcn_mfma_f32_16x16x32_bf16(aq1, bk1, s_acc[n], 0, 0, 0);
        }

        float s[4][4];
        const int cg0 = kt * 64 + fr;
#pragma unroll
        for (int i = 0; i < 4; ++i)
#pragma unroll
            for (int n = 0; n < 4; ++n) s[i][n] = s_acc[n][i] * 0.125f;
        if (CAUSAL && kt == qt) {
#pragma unroll
            for (int i = 0; i < 4; ++i)
#pragma unroll
                for (int n = 0; n < 4; ++n)
                    if (cg0 + n * 16 > rg0 + i) s[i][n] = -INFINITY;
        }
        if (!CAUSAL && kt == nkt - 1) {
#pragma unroll
            for (int i = 0; i < 4; ++i)
#pragma unroll
                for (int n = 0; n < 4; ++n)
                    if (cg0 + n * 16 >= Sk) s[i][n] = -INFINITY;
        }

        float mt[4], sf[4], rs[4];
#pragma unroll
        for (int i = 0; i < 4; ++i)
            mt[i] = fmaxf(fmaxf(s[i][0], s[i][1]), fmaxf(s[i][2], s[i][3]));
#pragma unroll
        for (int off = 1; off < 16; off <<= 1)
#pragma unroll
            for (int i = 0; i < 4; ++i) mt[i] = fmaxf(mt[i], __shfl_xor(mt[i], off));
#pragma unroll
        for (int i = 0; i < 4; ++i) {
            const float mn = fmaxf(m_run[i], mt[i]);
            sf[i] = expf(m_run[i] - mn);
            m_run[i] = mn;
            rs[i] = 0.0f;
#pragma unroll
            for (int n = 0; n < 4; ++n) {
                const float p = expf(s[i][n] - mn);
                s[i][n] = p;
                rs[i] += p;
            }
        }
#pragma unroll
        for (int off = 1; off < 16; off <<= 1)
#pragma unroll
            for (int i = 0; i < 4; ++i) rs[i] += __shfl_xor(rs[i], off);

#pragma unroll
        for (int i = 0; i < 4; ++i) {
            l_run[i] = l_run[i] * sf[i] + rs[i];
            const int pr = (w * 16 + fq * 4 + i) * LDA;
#pragma unroll
            for (int n = 0; n < 4; ++n)
                Ps[pr + n * 16 + fr] = f2b(s[i][n]);
        }
#pragma unroll
        for (int n = 0; n < 4; ++n)
#pragma unroll
            for (int i = 0; i < 4; ++i) o_acc[n][i] *= sf[i];
        __syncthreads();

        bf16x8 ap0 = *(const bf16x8*)&Ps[(w * 16 + fr) * LDA + fk];
        bf16x8 ap1 = *(const bf16x8*)&Ps[(w * 16 + fr) * LDA + 32 + fk];
#pragma unroll
        for (int n = 0; n < 4; ++n) {
            bf16x8 bv0 = *(const bf16x8*)&Vt[(n * 16 + fr) * LDA + fk];
            bf16x8 bv1 = *(const bf16x8*)&Vt[(n * 16 + fr) * LDA + 32 + fk];
            o_acc[n] = __builtin_amdgcn_mfma_f32_16x16x32_bf16(ap0, bv0, o_acc[n], 0, 0, 0);
            o_acc[n] = __builtin_amdgcn_mfma_f32_16x16x32_bf16(ap1, bv1, o_acc[n], 0, 0, 0);
        }
    }

#pragma unroll
    for (int i = 0; i < 4; ++i) {
        const float inv = 1.0f / l_run[i];
        const size_t r = (size_t)(b * Sq + qt * 64 + w * 16 + fq * 4 + i);
#pragma unroll
        for (int n = 0; n < 4; ++n)
            O[r * D_MODEL + h * DHEAD + n * 16 + fr] = f2b(o_acc[n][i] * inv);
    }
}

// ---------------------------------------------------------------------------
// Orchestration
// ---------------------------------------------------------------------------
extern "C" void kernel_launch(void* const* d_in, const int* in_sizes, int n_in,
                              void* d_out, int out_size, void* d_ws, size_t ws_size,
                              hipStream_t stream)
{
    const int B = 4, S = 1024, T = 1500, DFF = 4096;
    const int MS = B * S;    // 4096
    const int MT = B * T;    // 6000
    const int MTP = 6016;    // padded to x128

    const float* x          = (const float*)d_in[0];
    const float* xa         = (const float*)d_in[1];
    const float* attn_ln_g  = (const float*)d_in[3];
    const float* attn_ln_b  = (const float*)d_in[4];
    const float* sa_wq      = (const float*)d_in[5];
    const float* sa_bq      = (const float*)d_in[6];
    const float* sa_wk      = (const float*)d_in[7];
    const float* sa_wv      = (const float*)d_in[8];
    const float* sa_bv      = (const float*)d_in[9];
    const float* sa_wo      = (const float*)d_in[10];
    const float* sa_bo      = (const float*)d_in[11];
    const float* cross_ln_g = (const float*)d_in[12];
    const float* cross_ln_b = (const float*)d_in[13];
    const float* ca_wq      = (const float*)d_in[14];
    const float* ca_bq      = (const float*)d_in[15];
    const float* ca_wk      = (const float*)d_in[16];
    const float* ca_wv      = (const float*)d_in[17];
    const float* ca_bv      = (const float*)d_in[18];
    const float* ca_wo      = (const float*)d_in[19];
    const float* ca_bo      = (const float*)d_in[20];
    const float* mlp_ln_g   = (const float*)d_in[21];
    const float* mlp_ln_b   = (const float*)d_in[22];
    const float* mlp_w1     = (const float*)d_in[23];
    const float* mlp_b1     = (const float*)d_in[24];
    const float* mlp_w2     = (const float*)d_in[25];
    const float* mlp_b2     = (const float*)d_in[26];

    char* base = (char*)d_ws;
    size_t off = 0;
    auto alloc = [&](size_t bytes) -> void* {
        void* p = base + off; off += (bytes + 255) & ~(size_t)255; return p;
    };

    typedef unsigned short u16;
    const size_t DD2 = (size_t)D_MODEL * D_MODEL * 2;
    u16* sa_wqT = (u16*)alloc(DD2);
    u16* sa_wkT = (u16*)alloc(DD2);
    u16* sa_wvT = (u16*)alloc(DD2);
    u16* sa_woT = (u16*)alloc(DD2);
    u16* ca_wqT = (u16*)alloc(DD2);
    u16* ca_wkT = (u16*)alloc(DD2);
    u16* ca_wvT = (u16*)alloc(DD2);
    u16* ca_woT = (u16*)alloc(DD2);
    u16* w1T    = (u16*)alloc((size_t)D_MODEL * DFF * 2);   // [DFF][D]
    u16* w2T    = (u16*)alloc((size_t)D_MODEL * DFF * 2);   // [D][DFF]

    u16*   lnb = (u16*)alloc((size_t)MS * D_MODEL * 2);
    float* r1  = (float*)alloc((size_t)MS * D_MODEL * 4);
    u16*   ab  = (u16*)alloc((size_t)MS * D_MODEL * 2);

    char* qkv0 = (char*)alloc((size_t)MS * D_MODEL * 2      // qb
                            + (size_t)MTP * D_MODEL * 2     // kb
                            + (size_t)MTP * D_MODEL * 2     // vb
                            + (size_t)MTP * D_MODEL * 2);   // xab
    u16* qb  = (u16*)qkv0;
    u16* kb  = qb + (size_t)MS * D_MODEL;
    u16* vb  = kb + (size_t)MTP * D_MODEL;
    u16* xab = vb + (size_t)MTP * D_MODEL;
    u16* hb  = (u16*)qkv0;   // [MS][DFF] aliases q/k/v (+xab) region in MLP phase

    // ---- prep: weight transpose+convert, xa convert ----
    dim3 tb(32, 8);
    wtrans_kernel<<<dim3(D_MODEL/32, D_MODEL/32), tb, 0, stream>>>(sa_wq, sa_wqT, D_MODEL, D_MODEL);
    wtrans_kernel<<<dim3(D_MODEL/32, D_MODEL/32), tb, 0, stream>>>(sa_wk, sa_wkT, D_MODEL, D_MODEL);
    wtrans_kernel<<<dim3(D_MODEL/32, D_MODEL/32), tb, 0, stream>>>(sa_wv, sa_wvT, D_MODEL, D_MODEL);
    wtrans_kernel<<<dim3(D_MODEL/32, D_MODEL/32), tb, 0, stream>>>(sa_wo, sa_woT, D_MODEL, D_MODEL);
    wtrans_kernel<<<dim3(D_MODEL/32, D_MODEL/32), tb, 0, stream>>>(ca_wq, ca_wqT, D_MODEL, D_MODEL);
    wtrans_kernel<<<dim3(D_MODEL/32, D_MODEL/32), tb, 0, stream>>>(ca_wk, ca_wkT, D_MODEL, D_MODEL);
    wtrans_kernel<<<dim3(D_MODEL/32, D_MODEL/32), tb, 0, stream>>>(ca_wv, ca_wvT, D_MODEL, D_MODEL);
    wtrans_kernel<<<dim3(D_MODEL/32, D_MODEL/32), tb, 0, stream>>>(ca_wo, ca_woT, D_MODEL, D_MODEL);
    wtrans_kernel<<<dim3(DFF/32, D_MODEL/32), tb, 0, stream>>>(mlp_w1, w1T, D_MODEL, DFF);
    wtrans_kernel<<<dim3(D_MODEL/32, DFF/32), tb, 0, stream>>>(mlp_w2, w2T, DFF, D_MODEL);
    f2b_kernel<<<1024, 256, 0, stream>>>(xa, xab, MT * D_MODEL / 4);

    auto gemm = [&](const u16* A, const u16* Wt, const float* bias, const float* resid,
                    void* C, int M, int N, int K, bool gelu, bool obf16) {
        dim3 grid(N / 128, (M + 127) / 128);
        if (gelu)            mfma_gemm<true,  true ><<<grid, 256, 0, stream>>>(A, Wt, bias, resid, C, M, N, K);
        else if (obf16)      mfma_gemm<false, true ><<<grid, 256, 0, stream>>>(A, Wt, bias, resid, C, M, N, K);
        else                 mfma_gemm<false, false><<<grid, 256, 0, stream>>>(A, Wt, bias, resid, C, M, N, K);
    };

    // ---- self-attention block ----
    ln_kernel<<<MS, 256, 0, stream>>>(x, attn_ln_g, attn_ln_b, lnb);
    gemm(lnb, sa_wqT, sa_bq, nullptr, qb, MS, D_MODEL, D_MODEL, false, true);
    gemm(lnb, sa_wkT, nullptr, nullptr, kb, MS, D_MODEL, D_MODEL, false, true);
    gemm(lnb, sa_wvT, sa_bv, nullptr, vb, MS, D_MODEL, D_MODEL, false, true);
    mfattn_kernel<true><<<dim3(S / 64, NH, B), 256, 0, stream>>>(qb, kb, vb, ab, S, S);
    gemm(ab, sa_woT, sa_bo, x, r1, MS, D_MODEL, D_MODEL, false, false);

    // ---- cross-attention block ----
    ln_kernel<<<MS, 256, 0, stream>>>(r1, cross_ln_g, cross_ln_b, lnb);
    gemm(lnb, ca_wqT, ca_bq, nullptr, qb, MS, D_MODEL, D_MODEL, false, true);
    gemm(xab, ca_wkT, nullptr, nullptr, kb, MT, D_MODEL, D_MODEL, false, true);
    gemm(xab, ca_wvT, ca_bv, nullptr, vb, MT, D_MODEL, D_MODEL, false, true);
    mfattn_kernel<false><<<dim3(S / 64, NH, B), 256, 0, stream>>>(qb, kb, vb, ab, S, T);
    gemm(ab, ca_woT, ca_bo, r1, r1, MS, D_MODEL, D_MODEL, false, false);

    // ---- MLP block ----
    ln_kernel<<<MS, 256, 0, stream>>>(r1, mlp_ln_g, mlp_ln_b, lnb);
    gemm(lnb, w1T, mlp_b1, nullptr, hb, MS, DFF, D_MODEL, true, true);
    gemm(hb, w2T, mlp_b2, r1, d_out, MS, D_MODEL, DFF, false, false);
}